// Round 1
// baseline (222.537 us; speedup 1.0000x reference)
//
#include <hip/hip_runtime.h>
#include <math.h>

// Problem constants (from reference): x[32,4096,32] f32, codebook[256,32] f32
constexpr int D = 32;
constexpr int K = 256;
constexpr int ROWS_PER_BLOCK = 256;

// Output layout (concatenated float32, reference return order):
//   o_idx[N], o_probs[N*K], o_quants[N*D], o_loss[N]

__global__ __launch_bounds__(256) void vq_kernel(
    const float* __restrict__ x,
    const float* __restrict__ cb,
    float* __restrict__ o_idx,
    float* __restrict__ o_probs,
    float* __restrict__ o_quants,
    float* __restrict__ o_loss)
{
    __shared__ float cn[K];           // per-code squared norms
    __shared__ float pbuf[32][257];   // transpose buffer, +1 pad breaks bank conflicts

    const int tid = threadIdx.x;
    const int n   = blockIdx.x * ROWS_PER_BLOCK + tid;

    // --- per-code squared norm, one code per thread (K == blockDim.x == 256) ---
    {
        const float4* c4 = reinterpret_cast<const float4*>(cb) + tid * (D / 4);
        float a0 = 0.f, a1 = 0.f, a2 = 0.f, a3 = 0.f;
        #pragma unroll
        for (int i = 0; i < D / 4; ++i) {
            float4 c = c4[i];
            a0 += c.x * c.x; a1 += c.y * c.y; a2 += c.z * c.z; a3 += c.w * c.w;
        }
        cn[tid] = (a0 + a1) + (a2 + a3);
    }

    // --- load this thread's x row into registers ---
    float xr[D];
    {
        const float4* xv = reinterpret_cast<const float4*>(x) + (size_t)n * (D / 4);
        #pragma unroll
        for (int i = 0; i < D / 4; ++i) {
            float4 v = xv[i];
            xr[4 * i + 0] = v.x; xr[4 * i + 1] = v.y;
            xr[4 * i + 2] = v.z; xr[4 * i + 3] = v.w;
        }
    }
    float xx;
    {
        float a0 = 0.f, a1 = 0.f, a2 = 0.f, a3 = 0.f;
        #pragma unroll
        for (int j = 0; j < D; j += 4) {
            a0 += xr[j] * xr[j];     a1 += xr[j + 1] * xr[j + 1];
            a2 += xr[j + 2] * xr[j + 2]; a3 += xr[j + 3] * xr[j + 3];
        }
        xx = (a0 + a1) + (a2 + a3);
    }
    __syncthreads();

    // --- pass 1: online softmax + argmax over logits_k = 2*dot_k - (xx + cn_k) ---
    // Strictly-greater update keeps the FIRST max (matches jnp.argmax tie rule).
    float m = -INFINITY, s = 0.f;
    int bidx = 0;
    #pragma unroll 2
    for (int k = 0; k < K; ++k) {
        const float* c = cb + k * D;   // k is wave-uniform -> scalar loads
        float d0 = 0.f, d1 = 0.f, d2 = 0.f, d3 = 0.f;
        #pragma unroll
        for (int j = 0; j < D; j += 4) {
            d0 += xr[j] * c[j];         d1 += xr[j + 1] * c[j + 1];
            d2 += xr[j + 2] * c[j + 2]; d3 += xr[j + 3] * c[j + 3];
        }
        float dot = (d0 + d1) + (d2 + d3);
        float lg  = 2.0f * dot - (xx + cn[k]);   // = -d2, same assoc as reference
        bool  gt  = lg > m;
        bidx      = gt ? k : bidx;
        float mn  = gt ? lg : m;
        s = s * __expf(m - mn) + __expf(lg - mn);
        m = mn;
    }

    o_idx[n] = (float)bidx;

    // --- gather chosen code: quants output + loss (computed directly like ref) ---
    {
        const float4* cg = reinterpret_cast<const float4*>(cb) + bidx * (D / 4);
        float4* qv = reinterpret_cast<float4*>(o_quants) + (size_t)n * (D / 4);
        float a0 = 0.f, a1 = 0.f, a2 = 0.f, a3 = 0.f;
        #pragma unroll
        for (int i = 0; i < D / 4; ++i) {
            float4 c = cg[i];
            qv[i] = c;   // forward value of straight-through quants == codebook row
            float e0 = c.x - xr[4 * i + 0], e1 = c.y - xr[4 * i + 1];
            float e2 = c.z - xr[4 * i + 2], e3 = c.w - xr[4 * i + 3];
            a0 += e0 * e0; a1 += e1 * e1; a2 += e2 * e2; a3 += e3 * e3;
        }
        // loss = codebook_loss + MU*commitment = (1+0.25) * mean((c-x)^2)
        o_loss[n] = ((a0 + a1) + (a2 + a3)) * (1.25f / (float)D);
    }

    // --- pass 2: probs, staged through LDS for coalesced 128B-line stores ---
    const float rs = 1.0f / s;
    const int rowbase = blockIdx.x * ROWS_PER_BLOCK;
    float4* op = reinterpret_cast<float4*>(o_probs);
    for (int cch = 0; cch < 8; ++cch) {          // 8 chunks of 32 codes
        #pragma unroll 2
        for (int kl = 0; kl < 32; ++kl) {
            int k = cch * 32 + kl;
            const float* c = cb + k * D;
            float d0 = 0.f, d1 = 0.f, d2 = 0.f, d3 = 0.f;
            #pragma unroll
            for (int j = 0; j < D; j += 4) {
                d0 += xr[j] * c[j];         d1 += xr[j + 1] * c[j + 1];
                d2 += xr[j + 2] * c[j + 2]; d3 += xr[j + 3] * c[j + 3];
            }
            float dot = (d0 + d1) + (d2 + d3);
            float lg  = 2.0f * dot - (xx + cn[k]);
            pbuf[kl][tid] = __expf(lg - m) * rs;
        }
        __syncthreads();
        // cooperative coalesced write: 256 rows x 32 codes = 2048 float4
        #pragma unroll
        for (int i = 0; i < 8; ++i) {
            int e   = i * 256 + tid;
            int row = e >> 3;    // 8 float4 per row-chunk
            int jv  = e & 7;
            float4 v;
            v.x = pbuf[4 * jv + 0][row];
            v.y = pbuf[4 * jv + 1][row];
            v.z = pbuf[4 * jv + 2][row];
            v.w = pbuf[4 * jv + 3][row];
            op[(size_t)(rowbase + row) * (K / 4) + cch * 8 + jv] = v;
        }
        __syncthreads();
    }
}

extern "C" void kernel_launch(void* const* d_in, const int* in_sizes, int n_in,
                              void* d_out, int out_size, void* d_ws, size_t ws_size,
                              hipStream_t stream) {
    const float* x  = (const float*)d_in[0];
    const float* cb = (const float*)d_in[1];
    const int N = in_sizes[0] / D;   // 131072

    float* out      = (float*)d_out;
    float* o_idx    = out;
    float* o_probs  = o_idx + N;
    float* o_quants = o_probs + (size_t)N * K;
    float* o_loss   = o_quants + (size_t)N * D;

    const int grid = N / ROWS_PER_BLOCK;   // 512 blocks of 256 threads
    vq_kernel<<<grid, ROWS_PER_BLOCK, 0, stream>>>(x, cb, o_idx, o_probs, o_quants, o_loss);
}